// Round 4
// baseline (1192.480 us; speedup 1.0000x reference)
//
#include <hip/hip_runtime.h>
#include <hip/hip_bf16.h>
#include <math.h>

#define LEAKY(x) ((x) >= 0.0f ? (x) : 0.01f * (x))

// ======================= graph build (counting sort by dst) =======================
__global__ void k_zero(int* counts, int n) {
  int i = blockIdx.x * 256 + threadIdx.x;
  if (i < n) counts[i] = 0;
}

__global__ void k_count(const int* __restrict__ ei, int* counts, int E) {
  int e = blockIdx.x * 256 + threadIdx.x;
  if (e < E) atomicAdd(&counts[ei[E + e]], 1);
}

__global__ void k_scan1(const int* __restrict__ counts, int* rowst, int* bsums, int N) {
  __shared__ int sd[256];
  int t = threadIdx.x;
  int i = blockIdx.x * 256 + t;
  int v = (i < N) ? counts[i] : 0;
  sd[t] = v;
  __syncthreads();
  for (int off = 1; off < 256; off <<= 1) {
    int add = (t >= off) ? sd[t - off] : 0;
    __syncthreads();
    sd[t] += add;
    __syncthreads();
  }
  if (i < N) rowst[i] = sd[t] - v;          // block-local exclusive
  if (t == 255) bsums[blockIdx.x] = sd[255];
}

__global__ void k_scan2(int* bsums, int NB) {
  __shared__ int sd[256];
  int t = threadIdx.x;
  int v = (t < NB) ? bsums[t] : 0;
  sd[t] = v;
  __syncthreads();
  for (int off = 1; off < 256; off <<= 1) {
    int add = (t >= off) ? sd[t - off] : 0;
    __syncthreads();
    sd[t] += add;
    __syncthreads();
  }
  if (t < NB) bsums[t] = sd[t] - v;         // exclusive block offsets
}

__global__ void k_scan3(int* rowst, int* cursor, const int* bsums, int N, int E) {
  int i = blockIdx.x * 256 + threadIdx.x;
  if (i < N) {
    int v = rowst[i] + bsums[i >> 8];
    rowst[i] = v;
    cursor[i] = v;
  }
  if (i == 0) rowst[N] = E;
}

__global__ void k_place(const int* __restrict__ ei, const int* __restrict__ et,
                        int* cursor, unsigned* packed, int E) {
  int e = blockIdx.x * 256 + threadIdx.x;
  if (e < E) {
    int d = ei[E + e];
    int s = ei[e];
    int r = et[e]; r = r < 0 ? 0 : (r > 1 ? 1 : r);
    int pos = atomicAdd(&cursor[d], 1);
    packed[pos] = (unsigned)s | ((unsigned)r << 30);
  }
}

// e_rel[layer][rel][c] = rel_emb[rel] @ We_layer   (only 2 rel types)
__global__ void k_erel(const float* __restrict__ rel_emb, const float* __restrict__ We1,
                       const float* __restrict__ We2, float* erel) {
  int t = threadIdx.x;  // 512
  int layer = t >> 8, r = (t >> 7) & 1, c = t & 127;
  const float* We = layer ? We2 : We1;
  float s = 0.f;
  for (int i = 0; i < 128; i++) s += rel_emb[r * 128 + i] * We[i * 128 + c];
  erel[t] = s;
}

// =============== stage 1: modality MLPs (desc/tweet) -> m[N,128] cols 0..63 ======
// 64-row tile, 128 threads, 4x4 thread tile, register-prefetch pipeline.
// grid (ceil(N/64), 2): blockIdx.y 0=desc, 1=tweet
__global__ __launch_bounds__(128) void k_modal(
    const float* __restrict__ desc, const float* __restrict__ tw,
    const float* __restrict__ Wd, const float* __restrict__ bd,
    const float* __restrict__ Wt, const float* __restrict__ bt,
    float* __restrict__ m, int N) {
  __shared__ float As[32][68];    // transposed A chunk: As[k][r], 64 rows
  __shared__ float Bs[32][36];
  int t = threadIdx.x;
  int phase = blockIdx.y;
  const float* Ag = phase ? tw : desc;
  const float* W  = phase ? Wt : Wd;
  const float* bb = phase ? bt : bd;
  int n0 = blockIdx.x * 64;
  int tx = t & 7, ty = t >> 3;           // cols tx*4 (of 32), rows ty*4 (of 64)
  int tx4 = tx * 4, ty4 = ty * 4;

  // staging indices
  int sr = t >> 1, shalf = t & 1;        // A: row sr, k-range shalf*16..+16
  int skr = t >> 2, sc8 = (t & 3) * 8;   // B: k-row skr, cols sc8..+8
  int gr_ld = n0 + sr; if (gr_ld > N - 1) gr_ld = N - 1;
  const float* arow = Ag + (size_t)gr_ld * 768 + shalf * 16;

  float acc[4][4];
#pragma unroll
  for (int i = 0; i < 4; i++)
#pragma unroll
    for (int j = 0; j < 4; j++) acc[i][j] = 0.f;

  // prologue: load chunk 0 into regs
  float4 ar[4], br[2];
#pragma unroll
  for (int q = 0; q < 4; q++) ar[q] = *(const float4*)(arow + q * 4);
  {
    const float* wsrc = W + (size_t)skr * 32 + sc8;
    br[0] = *(const float4*)(wsrc);
    br[1] = *(const float4*)(wsrc + 4);
  }

  for (int ck = 0; ck < 24; ck++) {
    __syncthreads();   // previous compute done before overwriting LDS
    {
      int kb = shalf * 16;
#pragma unroll
      for (int q = 0; q < 4; q++) {
        float4 v = ar[q];
        As[kb + q * 4 + 0][sr] = v.x; As[kb + q * 4 + 1][sr] = v.y;
        As[kb + q * 4 + 2][sr] = v.z; As[kb + q * 4 + 3][sr] = v.w;
      }
      *(float4*)&Bs[skr][sc8] = br[0];
      *(float4*)&Bs[skr][sc8 + 4] = br[1];
    }
    // issue next chunk's global loads (in flight during compute)
    if (ck + 1 < 24) {
      int kc = (ck + 1) * 32;
      const float* an = arow + kc;
#pragma unroll
      for (int q = 0; q < 4; q++) ar[q] = *(const float4*)(an + q * 4);
      const float* wsrc = W + (size_t)(kc + skr) * 32 + sc8;
      br[0] = *(const float4*)(wsrc);
      br[1] = *(const float4*)(wsrc + 4);
    }
    __syncthreads();
#pragma unroll 8
    for (int k = 0; k < 32; k++) {
      float4 a0 = *(const float4*)&As[k][ty4];
      float4 b0 = *(const float4*)&Bs[k][tx4];
      float a[4] = {a0.x, a0.y, a0.z, a0.w};
#pragma unroll
      for (int i = 0; i < 4; i++) {
        acc[i][0] += a[i] * b0.x; acc[i][1] += a[i] * b0.y;
        acc[i][2] += a[i] * b0.z; acc[i][3] += a[i] * b0.w;
      }
    }
  }
  float4 bv = *(const float4*)&bb[tx4];
#pragma unroll
  for (int i = 0; i < 4; i++) {
    int gr = n0 + ty4 + i;
    if (gr < N) {
      float4 v;
      v.x = acc[i][0] + bv.x; v.y = acc[i][1] + bv.y;
      v.z = acc[i][2] + bv.z; v.w = acc[i][3] + bv.w;
      v.x = LEAKY(v.x); v.y = LEAKY(v.y); v.z = LEAKY(v.z); v.w = LEAKY(v.w);
      *(float4*)(m + (size_t)gr * 128 + phase * 32 + tx4) = v;
    }
  }
}

// num (Din=5) and cat (Din=3) -> m cols 64..127
__global__ __launch_bounds__(256) void k_numcat(
    const float* __restrict__ nump, const float* __restrict__ catp,
    const float* __restrict__ Wn, const float* __restrict__ bn,
    const float* __restrict__ Wc, const float* __restrict__ bc,
    float* __restrict__ m, int N) {
  int t = threadIdx.x;
  int n0 = blockIdx.x * 64;
  int c = t & 31, ty = t >> 5;
  float bn_ = bn[c], bc_ = bc[c];
#pragma unroll
  for (int j = 0; j < 8; j++) {
    int gr = n0 + ty * 8 + j;
    int gl = gr > N - 1 ? N - 1 : gr;
    float sn = bn_;
#pragma unroll
    for (int i = 0; i < 5; i++) sn += nump[(size_t)gl * 5 + i] * Wn[i * 32 + c];
    float sc = bc_;
#pragma unroll
    for (int i = 0; i < 3; i++) sc += catp[(size_t)gl * 3 + i] * Wc[i * 32 + c];
    if (gr < N) {
      m[(size_t)gr * 128 + 64 + c] = LEAKY(sn);
      m[(size_t)gr * 128 + 96 + c] = LEAKY(sc);
    }
  }
}

// ============ stage 2a: inv/spec projectors -> ch[N,256], aux partials ============
__global__ __launch_bounds__(256) void k_chfuse(
    const float* __restrict__ m, const float* __restrict__ Winv, const float* __restrict__ binv,
    const float* __restrict__ Wspec, const float* __restrict__ bspec,
    float* __restrict__ ch, float* __restrict__ auxp, int N) {
  __shared__ float sm[4][128];
  __shared__ float sch[4][256];
  int t = threadIdx.x;
  int wid = t >> 6, lane = t & 63;
  int n = blockIdx.x * 4 + wid;
  if (n > N - 1) n = N - 1;
  sm[wid][lane] = m[(size_t)n * 128 + lane];
  sm[wid][lane + 64] = m[(size_t)n * 128 + 64 + lane];
  __syncthreads();
#pragma unroll
  for (int p = 0; p < 4; p++) {
    int idx = p * 64 + lane;
    int type = idx >> 7;        // wave-uniform per p
    int k = (idx >> 5) & 3;
    int o = idx & 31;
    const float* W = type ? Wspec : Winv;
    const float* bb = type ? bspec : binv;
    float s = bb[k * 32 + o];
    for (int i = 0; i < 32; i++) s += sm[wid][k * 32 + i] * W[(k * 32 + i) * 32 + o];
    float val = type ? LEAKY(s) : tanhf(s);
    sch[wid][k * 64 + type * 32 + o] = val;  // [tok][inv(32)|spec(32)] = CH layout
  }
  __syncthreads();
  *(float4*)(ch + (size_t)n * 256 + lane * 4) = *(const float4*)&sch[wid][lane * 4];
  // aux partials
  float invp = 0.f;
  float pr[10];
#pragma unroll
  for (int q = 0; q < 10; q++) pr[q] = 0.f;
  if (lane < 32) {
    float i0 = sch[wid][lane],       i1 = sch[wid][64 + lane];
    float i2 = sch[wid][128 + lane], i3 = sch[wid][192 + lane];
    float cm = 0.25f * (i0 + i1 + i2 + i3);
    float d0 = i0 - cm, d1 = i1 - cm, d2 = i2 - cm, d3 = i3 - cm;
    invp = d0 * d0 + d1 * d1 + d2 * d2 + d3 * d3;
    float s0 = sch[wid][32 + lane],  s1 = sch[wid][96 + lane];
    float s2 = sch[wid][160 + lane], s3 = sch[wid][224 + lane];
    pr[0] = s0 * s0; pr[1] = s1 * s1; pr[2] = s2 * s2; pr[3] = s3 * s3;
    pr[4] = s0 * s1; pr[5] = s0 * s2; pr[6] = s0 * s3;
    pr[7] = s1 * s2; pr[8] = s1 * s3; pr[9] = s2 * s3;
  }
#pragma unroll
  for (int off = 1; off < 64; off <<= 1) {
    invp += __shfl_xor(invp, off);
#pragma unroll
    for (int q = 0; q < 10; q++) pr[q] += __shfl_xor(pr[q], off);
  }
  if (lane == 0) {
    float n0_ = sqrtf(pr[0]), n1_ = sqrtf(pr[1]), n2_ = sqrtf(pr[2]), n3_ = sqrtf(pr[3]);
    float ov = fabsf(pr[4] / fmaxf(n0_ * n1_, 1e-8f))
             + fabsf(pr[5] / fmaxf(n0_ * n2_, 1e-8f))
             + fabsf(pr[6] / fmaxf(n0_ * n3_, 1e-8f))
             + fabsf(pr[7] / fmaxf(n1_ * n2_, 1e-8f))
             + fabsf(pr[8] / fmaxf(n1_ * n3_, 1e-8f))
             + fabsf(pr[9] / fmaxf(n2_ * n3_, 1e-8f));
    auxp[n] = invp / 128.f + 0.5f * (ov / 6.f);
  }
}

// ========== stage 2b-1: qkv GEMM (tokens[4N,64] @ Wqkv[64,192]) + channel attn ====
// 128 tokens (32 nodes) per block, 256 threads, 8x12 thread tile. qkv stays in LDS.
__global__ __launch_bounds__(256) void k_qkvattn(
    const float* __restrict__ ch, const float* __restrict__ Wqkv,
    const float* __restrict__ bqkv, float* __restrict__ att, int N4) {
  __shared__ float As[32][132];   // ch chunk, transposed
  __shared__ float Bs[32][200];   // Wqkv chunk
  __shared__ float qb[128][200];  // qkv for 128 tokens (cols: q 0-63, k 64-127, v 128-191)
  int t = threadIdx.x;
  int tok0 = blockIdx.x * 128;
  int tx = t & 15, ty = t >> 4;   // cols tx*12.., rows ty*8..
  float acc[8][12];
#pragma unroll
  for (int i = 0; i < 8; i++)
#pragma unroll
    for (int j = 0; j < 12; j++) acc[i][j] = 0.f;

  for (int kc = 0; kc < 64; kc += 32) {
    __syncthreads();
    {  // stage A transposed: r = t>>1, half = t&1 -> 16 k values
      int r = t >> 1, half = t & 1;
      int gtok = tok0 + r; if (gtok > N4 - 1) gtok = N4 - 1;
      const float4* src = (const float4*)(ch + (size_t)gtok * 64 + kc + half * 16);
      int kb = half * 16;
#pragma unroll
      for (int q = 0; q < 4; q++) {
        float4 v = src[q];
        As[kb + q * 4 + 0][r] = v.x; As[kb + q * 4 + 1][r] = v.y;
        As[kb + q * 4 + 2][r] = v.z; As[kb + q * 4 + 3][r] = v.w;
      }
      // stage B: rows kr, kr+16; cols (t&15)*12
      int kr = t >> 4, cq = (t & 15) * 12;
#pragma unroll
      for (int rr = 0; rr < 2; rr++) {
        int row = kr + rr * 16;
        const float* wsrc = Wqkv + (size_t)(kc + row) * 192 + cq;
        *(float4*)&Bs[row][cq] = *(const float4*)(wsrc);
        *(float4*)&Bs[row][cq + 4] = *(const float4*)(wsrc + 4);
        *(float4*)&Bs[row][cq + 8] = *(const float4*)(wsrc + 8);
      }
    }
    __syncthreads();
#pragma unroll 8
    for (int k = 0; k < 32; k++) {
      float4 a0 = *(const float4*)&As[k][ty * 8];
      float4 a1 = *(const float4*)&As[k][ty * 8 + 4];
      float4 b0 = *(const float4*)&Bs[k][tx * 12];
      float4 b1 = *(const float4*)&Bs[k][tx * 12 + 4];
      float4 b2 = *(const float4*)&Bs[k][tx * 12 + 8];
      float a[8] = {a0.x, a0.y, a0.z, a0.w, a1.x, a1.y, a1.z, a1.w};
      float b[12] = {b0.x, b0.y, b0.z, b0.w, b1.x, b1.y, b1.z, b1.w,
                     b2.x, b2.y, b2.z, b2.w};
#pragma unroll
      for (int i = 0; i < 8; i++)
#pragma unroll
        for (int j = 0; j < 12; j++) acc[i][j] += a[i] * b[j];
    }
  }
  // bias + write qkv to LDS
  float4 bb0 = *(const float4*)&bqkv[tx * 12];
  float4 bb1 = *(const float4*)&bqkv[tx * 12 + 4];
  float4 bb2 = *(const float4*)&bqkv[tx * 12 + 8];
  __syncthreads();
#pragma unroll
  for (int i = 0; i < 8; i++) {
    int row = ty * 8 + i;
    float4 v0, v1, v2;
    v0.x = acc[i][0] + bb0.x; v0.y = acc[i][1] + bb0.y;
    v0.z = acc[i][2] + bb0.z; v0.w = acc[i][3] + bb0.w;
    v1.x = acc[i][4] + bb1.x; v1.y = acc[i][5] + bb1.y;
    v1.z = acc[i][6] + bb1.z; v1.w = acc[i][7] + bb1.w;
    v2.x = acc[i][8] + bb2.x; v2.y = acc[i][9] + bb2.y;
    v2.z = acc[i][10] + bb2.z; v2.w = acc[i][11] + bb2.w;
    *(float4*)&qb[row][tx * 12] = v0;
    *(float4*)&qb[row][tx * 12 + 4] = v1;
    *(float4*)&qb[row][tx * 12 + 8] = v2;
  }
  __syncthreads();
  // channel attention: thread (g,h) handles node g (32/block), head h, all 4 q-tokens
  {
    int g = t >> 3, h = t & 7;
    int rb = g * 4;
    float kk[4][8], vv[4][8];
#pragma unroll
    for (int j = 0; j < 4; j++)
#pragma unroll
      for (int dd = 0; dd < 8; dd++) {
        kk[j][dd] = qb[rb + j][64 + h * 8 + dd];
        vv[j][dd] = qb[rb + j][128 + h * 8 + dd];
      }
#pragma unroll
    for (int qi = 0; qi < 4; qi++) {
      float qv[8];
#pragma unroll
      for (int dd = 0; dd < 8; dd++) qv[dd] = qb[rb + qi][h * 8 + dd];
      float sc[4];
#pragma unroll
      for (int j = 0; j < 4; j++) {
        float s = 0.f;
#pragma unroll
        for (int dd = 0; dd < 8; dd++) s += qv[dd] * kk[j][dd];
        sc[j] = s * 0.35355339059327373f;  // 1/sqrt(8)
      }
      float mx = fmaxf(fmaxf(sc[0], sc[1]), fmaxf(sc[2], sc[3]));
      float e0 = expf(sc[0] - mx), e1 = expf(sc[1] - mx);
      float e2 = expf(sc[2] - mx), e3 = expf(sc[3] - mx);
      float inv = 1.f / (e0 + e1 + e2 + e3);
      int token = tok0 + rb + qi;
      if (token < N4) {
        float o[8];
#pragma unroll
        for (int dd = 0; dd < 8; dd++)
          o[dd] = (e0 * vv[0][dd] + e1 * vv[1][dd] + e2 * vv[2][dd] + e3 * vv[3][dd]) * inv;
        float* dst = att + (size_t)token * 64 + h * 8;
        float4 w0 = {o[0], o[1], o[2], o[3]};
        float4 w1 = {o[4], o[5], o[6], o[7]};
        *(float4*)(dst) = w0;
        *(float4*)(dst + 4) = w1;
      }
    }
  }
}

// ==== stage 2b-2: attn_out GEMM + bias + residual + LN + token-mean + c2h -> x0 ====
// 128 tokens (32 nodes) per block, 256 threads.
__global__ __launch_bounds__(256) void k_attnout(
    const float* __restrict__ att, const float* __restrict__ ch,
    const float* __restrict__ Wao, const float* __restrict__ bao,
    const float* __restrict__ lng, const float* __restrict__ lnb,
    const float* __restrict__ Wc2h, const float* __restrict__ bc2h,
    float* __restrict__ x0, int N, int N4) {
  __shared__ float As[32][132];
  __shared__ float Bs[32][132];
  __shared__ float hmT[64][36];   // transposed node-mean: hmT[k][node]
  int t = threadIdx.x;
  int tok0 = blockIdx.x * 128;
  int tx = t & 15, ty = t >> 4;   // cols tx*4 (of 64), rows ty*8 (of 128)
  float acc[8][4];
#pragma unroll
  for (int i = 0; i < 8; i++)
#pragma unroll
    for (int j = 0; j < 4; j++) acc[i][j] = 0.f;

  for (int kc = 0; kc < 64; kc += 32) {
    __syncthreads();
    {
      int r = t >> 1, half = t & 1;
      int gtok = tok0 + r; if (gtok > N4 - 1) gtok = N4 - 1;
      const float4* src = (const float4*)(att + (size_t)gtok * 64 + kc + half * 16);
      int kb = half * 16;
#pragma unroll
      for (int q = 0; q < 4; q++) {
        float4 v = src[q];
        As[kb + q * 4 + 0][r] = v.x; As[kb + q * 4 + 1][r] = v.y;
        As[kb + q * 4 + 2][r] = v.z; As[kb + q * 4 + 3][r] = v.w;
      }
      int kr = t >> 3, cq = (t & 7) * 8;
      const float4* wsrc = (const float4*)(Wao + (size_t)(kc + kr) * 64 + cq);
      *(float4*)&Bs[kr][cq] = wsrc[0];
      *(float4*)&Bs[kr][cq + 4] = wsrc[1];
    }
    __syncthreads();
#pragma unroll 8
    for (int k = 0; k < 32; k++) {
      float4 a0 = *(const float4*)&As[k][ty * 8];
      float4 a1 = *(const float4*)&As[k][ty * 8 + 4];
      float4 b0 = *(const float4*)&Bs[k][tx * 4];
      float a[8] = {a0.x, a0.y, a0.z, a0.w, a1.x, a1.y, a1.z, a1.w};
#pragma unroll
      for (int i = 0; i < 8; i++) {
        acc[i][0] += a[i] * b0.x; acc[i][1] += a[i] * b0.y;
        acc[i][2] += a[i] * b0.z; acc[i][3] += a[i] * b0.w;
      }
    }
  }
  // bias + residual + LayerNorm
  float4 bv = *(const float4*)&bao[tx * 4];
  float4 g4 = *(const float4*)&lng[tx * 4];
  float4 lb4 = *(const float4*)&lnb[tx * 4];
  float nv[8][4];
#pragma unroll
  for (int i = 0; i < 8; i++) {
    int row = ty * 8 + i;
    int gtok = tok0 + row; if (gtok > N4 - 1) gtok = N4 - 1;
    float4 c4 = *(const float4*)(ch + (size_t)gtok * 64 + tx * 4);
    float y0 = acc[i][0] + bv.x + c4.x;
    float y1 = acc[i][1] + bv.y + c4.y;
    float y2 = acc[i][2] + bv.z + c4.z;
    float y3 = acc[i][3] + bv.w + c4.w;
    float s1 = y0 + y1 + y2 + y3;
    s1 += __shfl_xor(s1, 1); s1 += __shfl_xor(s1, 2);
    s1 += __shfl_xor(s1, 4); s1 += __shfl_xor(s1, 8);
    float mu = s1 * (1.f / 64.f);
    float d0 = y0 - mu, d1 = y1 - mu, d2 = y2 - mu, d3 = y3 - mu;
    float s2 = d0 * d0 + d1 * d1 + d2 * d2 + d3 * d3;
    s2 += __shfl_xor(s2, 1); s2 += __shfl_xor(s2, 2);
    s2 += __shfl_xor(s2, 4); s2 += __shfl_xor(s2, 8);
    float rs = rsqrtf(s2 * (1.f / 64.f) + 1e-5f);
    nv[i][0] = d0 * rs * g4.x + lb4.x;
    nv[i][1] = d1 * rs * g4.y + lb4.y;
    nv[i][2] = d2 * rs * g4.z + lb4.z;
    nv[i][3] = d3 * rs * g4.w + lb4.w;
  }
  // token-mean -> hmT[k][node]  (thread owns 2 nodes x 4 k-cols)
#pragma unroll
  for (int ii = 0; ii < 2; ii++) {
    int node = ty * 2 + ii;
#pragma unroll
    for (int j = 0; j < 4; j++) {
      float mval = 0.25f * (nv[ii * 4 + 0][j] + nv[ii * 4 + 1][j]
                          + nv[ii * 4 + 2][j] + nv[ii * 4 + 3][j]);
      hmT[tx * 4 + j][node] = mval;
    }
  }
  // c2h GEMM: hm[32,64] @ Wc2h[64,128] -> leaky -> x0
  int tx2 = t & 31, ty2 = t >> 5;   // cols tx2*4 (of 128), nodes ty2*4 (of 32)
  float acc2[4][4];
#pragma unroll
  for (int i = 0; i < 4; i++)
#pragma unroll
    for (int j = 0; j < 4; j++) acc2[i][j] = 0.f;
  for (int kc = 0; kc < 64; kc += 32) {
    __syncthreads();
    {
      int kr = t >> 3, cq = (t & 7) * 16;
      const float4* wsrc = (const float4*)(Wc2h + (size_t)(kc + kr) * 128 + cq);
      *(float4*)&Bs[kr][cq] = wsrc[0];
      *(float4*)&Bs[kr][cq + 4] = wsrc[1];
      *(float4*)&Bs[kr][cq + 8] = wsrc[2];
      *(float4*)&Bs[kr][cq + 12] = wsrc[3];
    }
    __syncthreads();
#pragma unroll 8
    for (int kk = 0; kk < 32; kk++) {
      float4 a = *(const float4*)&hmT[kc + kk][ty2 * 4];
      float4 b = *(const float4*)&Bs[kk][tx2 * 4];
      float av[4] = {a.x, a.y, a.z, a.w};
#pragma unroll
      for (int i = 0; i < 4; i++) {
        acc2[i][0] += av[i] * b.x; acc2[i][1] += av[i] * b.y;
        acc2[i][2] += av[i] * b.z; acc2[i][3] += av[i] * b.w;
      }
    }
  }
  float4 bc4 = *(const float4*)&bc2h[tx2 * 4];
  int nb0 = blockIdx.x * 32;
#pragma unroll
  for (int i = 0; i < 4; i++) {
    int gn = nb0 + ty2 * 4 + i;
    if (gn < N) {
      float4 v;
      v.x = acc2[i][0] + bc4.x; v.y = acc2[i][1] + bc4.y;
      v.z = acc2[i][2] + bc4.z; v.w = acc2[i][3] + bc4.w;
      v.x = LEAKY(v.x); v.y = LEAKY(v.y); v.z = LEAKY(v.z); v.w = LEAKY(v.w);
      *(float4*)(x0 + (size_t)gn * 128 + tx2 * 4) = v;
    }
  }
}

// ====== register-tiled GEMM: out[:, cb*128..] = x[N,128] @ W_cb + b_cb =========
__global__ __launch_bounds__(256) void k_gemm(
    const float* __restrict__ x,
    const float* __restrict__ W0, const float* __restrict__ B0,
    const float* __restrict__ W1, const float* __restrict__ B1,
    const float* __restrict__ W2, const float* __restrict__ B2,
    const float* __restrict__ W3, const float* __restrict__ B3,
    float* __restrict__ out, int N, int ostride, int do_leaky) {
  __shared__ float As[32][132];   // As[k][r] transposed
  __shared__ float Bs[32][132];   // Bs[k][c]
  int t = threadIdx.x;
  int cb = blockIdx.y;
  const float* W = (cb == 0) ? W0 : (cb == 1) ? W1 : (cb == 2) ? W2 : W3;
  const float* bias = (cb == 0) ? B0 : (cb == 1) ? B1 : (cb == 2) ? B2 : B3;
  int n0 = blockIdx.x * 128;
  int tx = t & 15, ty = t >> 4;
  int tx4 = tx * 4, ty4 = (ty & 15) * 4;
  float acc[8][8];
#pragma unroll
  for (int i = 0; i < 8; i++)
#pragma unroll
    for (int j = 0; j < 8; j++) acc[i][j] = 0.f;

  for (int kc = 0; kc < 128; kc += 32) {
    __syncthreads();
    {
      int r = t >> 1, half = t & 1;
      int gr = n0 + r; if (gr > N - 1) gr = N - 1;
      const float4* src = (const float4*)(x + (size_t)gr * 128 + kc + half * 16);
      int kb = half * 16;
#pragma unroll
      for (int q = 0; q < 4; q++) {
        float4 v = src[q];
        As[kb + q * 4 + 0][r] = v.x; As[kb + q * 4 + 1][r] = v.y;
        As[kb + q * 4 + 2][r] = v.z; As[kb + q * 4 + 3][r] = v.w;
      }
      int kr = t >> 3, cq = (t & 7) * 16;
      const float4* ws4 = (const float4*)(W + (size_t)(kc + kr) * 128 + cq);
      *(float4*)&Bs[kr][cq] = ws4[0];
      *(float4*)&Bs[kr][cq + 4] = ws4[1];
      *(float4*)&Bs[kr][cq + 8] = ws4[2];
      *(float4*)&Bs[kr][cq + 12] = ws4[3];
    }
    __syncthreads();
#pragma unroll 4
    for (int k = 0; k < 32; k++) {
      float4 a0 = *(const float4*)&As[k][ty4];
      float4 a1 = *(const float4*)&As[k][64 + ty4];
      float4 b0 = *(const float4*)&Bs[k][tx4];
      float4 b1 = *(const float4*)&Bs[k][64 + tx4];
      float a[8] = {a0.x, a0.y, a0.z, a0.w, a1.x, a1.y, a1.z, a1.w};
      float b[8] = {b0.x, b0.y, b0.z, b0.w, b1.x, b1.y, b1.z, b1.w};
#pragma unroll
      for (int i = 0; i < 8; i++)
#pragma unroll
        for (int j = 0; j < 8; j++) acc[i][j] += a[i] * b[j];
    }
  }
  float4 bv0 = *(const float4*)&bias[tx4];
  float4 bv1 = *(const float4*)&bias[64 + tx4];
#pragma unroll
  for (int i = 0; i < 8; i++) {
    int r = (i < 4) ? (ty4 + i) : (60 + ty4 + i);
    int gr = n0 + r;
    if (gr < N) {
      float4 v0, v1;
      v0.x = acc[i][0] + bv0.x; v0.y = acc[i][1] + bv0.y;
      v0.z = acc[i][2] + bv0.z; v0.w = acc[i][3] + bv0.w;
      v1.x = acc[i][4] + bv1.x; v1.y = acc[i][5] + bv1.y;
      v1.z = acc[i][6] + bv1.z; v1.w = acc[i][7] + bv1.w;
      if (do_leaky) {
        v0.x = LEAKY(v0.x); v0.y = LEAKY(v0.y); v0.z = LEAKY(v0.z); v0.w = LEAKY(v0.w);
        v1.x = LEAKY(v1.x); v1.y = LEAKY(v1.y); v1.z = LEAKY(v1.z); v1.w = LEAKY(v1.w);
      }
      float* o = out + (size_t)gr * ostride + (size_t)cb * 128;
      *(float4*)(o + tx4) = v0;
      *(float4*)(o + 64 + tx4) = v1;
    }
  }
}

// ====== TransformerConv aggregation: one wave per dst node (CSR, no atomics) ======
__global__ __launch_bounds__(256) void k_conv(
    const float* __restrict__ qkvs, const int* __restrict__ rowst,
    const unsigned* __restrict__ packed, const float* __restrict__ erelL,
    float* __restrict__ xout, int N, int do_leaky) {
  __shared__ float se[2][128];
  int t = threadIdx.x;
  se[t >> 7][t & 127] = erelL[t];
  __syncthreads();
  int wid = t >> 6, lane = t & 63;
  int d = blockIdx.x * 4 + wid;
  if (d >= N) return;
  const float* qb = qkvs + (size_t)d * 512;
  float q0 = qb[lane], q1 = qb[64 + lane];
  int e0 = rowst[d], e1 = rowst[d + 1];
  float acc0 = 0.f, acc1 = 0.f, den0 = 0.f, den1 = 0.f;
  for (int e = e0; e < e1; e++) {
    unsigned pk = packed[e];
    int src = pk & 0x0FFFFFFFu;
    int rel = pk >> 30;
    const float* sb = qkvs + (size_t)src * 512;
    float ek0 = se[rel][lane], ek1 = se[rel][64 + lane];
    float k0 = sb[128 + lane] + ek0;
    float k1 = sb[192 + lane] + ek1;
    float v0 = sb[256 + lane] + ek0;
    float v1 = sb[320 + lane] + ek1;
    float p0 = q0 * k0, p1 = q1 * k1;
#pragma unroll
    for (int off = 1; off < 16; off <<= 1) {  // per-head (16-ch) reduce
      p0 += __shfl_xor(p0, off);
      p1 += __shfl_xor(p1, off);
    }
    float ex0 = expf(p0 * 0.25f);  // 1/sqrt(16); no max-sub needed (|alpha| small)
    float ex1 = expf(p1 * 0.25f);
    acc0 += ex0 * v0; den0 += ex0;
    acc1 += ex1 * v1; den1 += ex1;
  }
  float o0 = acc0 / (den0 + 1e-16f) + qb[384 + lane];
  float o1 = acc1 / (den1 + 1e-16f) + qb[448 + lane];
  if (do_leaky) { o0 = LEAKY(o0); o1 = LEAKY(o1); }
  xout[(size_t)d * 128 + lane] = o0;
  xout[(size_t)d * 128 + 64 + lane] = o1;
}

// ============== head: logits = x3 @ Whead + bhead  (32 nodes/block) ==============
__global__ __launch_bounds__(256) void k_head(
    const float* __restrict__ x3, const float* __restrict__ Wh,
    const float* __restrict__ bh, float* __restrict__ out, int N) {
  int t = threadIdx.x;
  int node = blockIdx.x * 32 + (t >> 3);
  int l8 = t & 7;
  int gl = node < N ? node : N - 1;
  const float4* xr = (const float4*)(x3 + (size_t)gl * 128 + l8 * 16);
  float h0 = 0.f, h1 = 0.f;
#pragma unroll
  for (int q = 0; q < 4; q++) {
    float4 v = xr[q];
    int kb = (l8 * 16 + q * 4) * 2;
    h0 += v.x * Wh[kb] + v.y * Wh[kb + 2] + v.z * Wh[kb + 4] + v.w * Wh[kb + 6];
    h1 += v.x * Wh[kb + 1] + v.y * Wh[kb + 3] + v.z * Wh[kb + 5] + v.w * Wh[kb + 7];
  }
#pragma unroll
  for (int off = 1; off < 8; off <<= 1) {
    h0 += __shfl_xor(h0, off);
    h1 += __shfl_xor(h1, off);
  }
  if (l8 == 0 && node < N) {
    float2 r; r.x = h0 + bh[0]; r.y = h1 + bh[1];
    *(float2*)(out + (size_t)node * 2) = r;
  }
}

__global__ void k_aux(const float* __restrict__ auxp, float* __restrict__ out, int N) {
  __shared__ float sd[256];
  int t = threadIdx.x;
  float s = 0.f;
  for (int i = t; i < N; i += 256) s += auxp[i];
  sd[t] = s;
  __syncthreads();
  for (int off = 128; off > 0; off >>= 1) {
    if (t < off) sd[t] += sd[t + off];
    __syncthreads();
  }
  if (t == 0) out[0] = 0.1f * sd[0] / (float)N;
}

extern "C" void kernel_launch(void* const* d_in, const int* in_sizes, int n_in,
                              void* d_out, int out_size, void* d_ws, size_t ws_size,
                              hipStream_t stream) {
  (void)n_in; (void)out_size; (void)ws_size;
  const float* desc = (const float*)d_in[0];
  const float* tw   = (const float*)d_in[1];
  const float* nump = (const float*)d_in[2];
  const float* catp = (const float*)d_in[3];
  const int* ei = (const int*)d_in[4];
  const int* et = (const int*)d_in[5];
  const float* Wd = (const float*)d_in[6];  const float* bd = (const float*)d_in[7];
  const float* Wt = (const float*)d_in[8];  const float* bt = (const float*)d_in[9];
  const float* Wn = (const float*)d_in[10]; const float* bn = (const float*)d_in[11];
  const float* Wc = (const float*)d_in[12]; const float* bc = (const float*)d_in[13];
  const float* Winv = (const float*)d_in[14]; const float* binv = (const float*)d_in[15];
  const float* Wspec = (const float*)d_in[16]; const float* bspec = (const float*)d_in[17];
  const float* Wqkv = (const float*)d_in[18]; const float* bqkv = (const float*)d_in[19];
  const float* Wao = (const float*)d_in[20]; const float* bao = (const float*)d_in[21];
  const float* lng = (const float*)d_in[22]; const float* lnb = (const float*)d_in[23];
  const float* Wc2h = (const float*)d_in[24]; const float* bc2h = (const float*)d_in[25];
  const float* rel_emb = (const float*)d_in[26];
  const float* Wq1 = (const float*)d_in[27]; const float* bq1 = (const float*)d_in[28];
  const float* Wk1 = (const float*)d_in[29]; const float* bk1 = (const float*)d_in[30];
  const float* Wv1 = (const float*)d_in[31]; const float* bv1 = (const float*)d_in[32];
  const float* We1 = (const float*)d_in[33];
  const float* Ws1 = (const float*)d_in[34]; const float* bs1 = (const float*)d_in[35];
  const float* Wq2 = (const float*)d_in[36]; const float* bq2 = (const float*)d_in[37];
  const float* Wk2 = (const float*)d_in[38]; const float* bk2 = (const float*)d_in[39];
  const float* Wv2 = (const float*)d_in[40]; const float* bv2 = (const float*)d_in[41];
  const float* We2 = (const float*)d_in[42];
  const float* Ws2 = (const float*)d_in[43]; const float* bs2 = (const float*)d_in[44];
  const float* Wout = (const float*)d_in[45]; const float* bout = (const float*)d_in[46];
  const float* Whead = (const float*)d_in[47]; const float* bhead = (const float*)d_in[48];

  int N = in_sizes[0] / 768;
  int E = in_sizes[5];
  int N4 = N * 4;
  float* out = (float*)d_out;

  // workspace layout (fp32): ~208 MB total
  float* ws = (float*)d_ws;
  size_t Ns = (size_t)N;
  float* m_buf    = ws;                    // N*128
  float* ch_buf   = m_buf + Ns * 128;      // N*256
  float* x0_buf   = ch_buf + Ns * 256;     // N*128
  float* qkvs_buf = x0_buf + Ns * 128;     // N*512
  float* auxp     = qkvs_buf + Ns * 512;   // N
  float* erel     = auxp + Ns;             // 512
  int* counts = (int*)(erel + 512);        // N
  int* rowst  = counts + N;                // N+1
  int* cursor = rowst + N + 1;             // N
  unsigned* packed = (unsigned*)(cursor + N);  // E
  int* bsums  = (int*)(packed + E);        // NB
  float* x1_buf = m_buf;                   // reuse (m dead after k_chfuse)
  float* x2_buf = ch_buf;                  // reuse (ch dead after k_attnout)
  float* x3_buf = x0_buf;                  // reuse (x0 dead after first k_gemm)
  float* att_buf = qkvs_buf;               // reuse (qkvs dead during stage2b; att = 4N*64 <= N*512)

  int NB = (N + 255) / 256;
  int EB = (E + 255) / 256;
  int GT = (N + 127) / 128;                // 128-row GEMM tiles
  int MT = (N + 63) / 64;                  // 64-row modal tiles
  int TT = (N4 + 127) / 128;               // 128-token tiles

  k_zero<<<NB, 256, 0, stream>>>(counts, N);
  k_count<<<EB, 256, 0, stream>>>(ei, counts, E);
  k_scan1<<<NB, 256, 0, stream>>>(counts, rowst, bsums, N);
  k_scan2<<<1, 256, 0, stream>>>(bsums, NB);
  k_scan3<<<NB, 256, 0, stream>>>(rowst, cursor, bsums, N, E);
  k_place<<<EB, 256, 0, stream>>>(ei, et, cursor, packed, E);
  k_erel<<<1, 512, 0, stream>>>(rel_emb, We1, We2, erel);

  k_modal<<<dim3(MT, 2), 128, 0, stream>>>(desc, tw, Wd, bd, Wt, bt, m_buf, N);
  k_numcat<<<(N + 63) / 64, 256, 0, stream>>>(nump, catp, Wn, bn, Wc, bc, m_buf, N);
  k_chfuse<<<(N + 3) / 4, 256, 0, stream>>>(m_buf, Winv, binv, Wspec, bspec,
      ch_buf, auxp, N);
  k_qkvattn<<<TT, 256, 0, stream>>>(ch_buf, Wqkv, bqkv, att_buf, N4);
  k_attnout<<<TT, 256, 0, stream>>>(att_buf, ch_buf, Wao, bao, lng, lnb,
      Wc2h, bc2h, x0_buf, N, N4);

  k_gemm<<<dim3(GT, 4), 256, 0, stream>>>(x0_buf, Wq1, bq1, Wk1, bk1,
      Wv1, bv1, Ws1, bs1, qkvs_buf, N, 512, 0);
  k_conv<<<(N + 3) / 4, 256, 0, stream>>>(qkvs_buf, rowst, packed, erel, x1_buf, N, 1);
  k_gemm<<<dim3(GT, 4), 256, 0, stream>>>(x1_buf, Wq2, bq2, Wk2, bk2,
      Wv2, bv2, Ws2, bs2, qkvs_buf, N, 512, 0);
  k_conv<<<(N + 3) / 4, 256, 0, stream>>>(qkvs_buf, rowst, packed, erel + 256, x2_buf, N, 0);

  k_gemm<<<dim3(GT, 1), 256, 0, stream>>>(x2_buf, Wout, bout, Wout, bout,
      Wout, bout, Wout, bout, x3_buf, N, 128, 1);
  k_head<<<(N + 31) / 32, 256, 0, stream>>>(x3_buf, Whead, bhead, out, N);
  k_aux<<<1, 256, 0, stream>>>(auxp, out + (size_t)2 * N, N);
}

// Round 5
// 1164.117 us; speedup vs baseline: 1.0244x; 1.0244x over previous
//
#include <hip/hip_runtime.h>
#include <hip/hip_bf16.h>
#include <math.h>

#define LEAKY(x) ((x) >= 0.0f ? (x) : 0.01f * (x))

// ======================= graph build (counting sort by dst) =======================
__global__ void k_zero(int* counts, int n) {
  int i = blockIdx.x * 256 + threadIdx.x;
  if (i < n) counts[i] = 0;
}

__global__ void k_count(const int* __restrict__ ei, int* counts, int E) {
  int e = blockIdx.x * 256 + threadIdx.x;
  if (e < E) atomicAdd(&counts[ei[E + e]], 1);
}

__global__ void k_scan1(const int* __restrict__ counts, int* rowst, int* bsums, int N) {
  __shared__ int sd[256];
  int t = threadIdx.x;
  int i = blockIdx.x * 256 + t;
  int v = (i < N) ? counts[i] : 0;
  sd[t] = v;
  __syncthreads();
  for (int off = 1; off < 256; off <<= 1) {
    int add = (t >= off) ? sd[t - off] : 0;
    __syncthreads();
    sd[t] += add;
    __syncthreads();
  }
  if (i < N) rowst[i] = sd[t] - v;          // block-local exclusive
  if (t == 255) bsums[blockIdx.x] = sd[255];
}

__global__ void k_scan2(int* bsums, int NB) {
  __shared__ int sd[256];
  int t = threadIdx.x;
  int v = (t < NB) ? bsums[t] : 0;
  sd[t] = v;
  __syncthreads();
  for (int off = 1; off < 256; off <<= 1) {
    int add = (t >= off) ? sd[t - off] : 0;
    __syncthreads();
    sd[t] += add;
    __syncthreads();
  }
  if (t < NB) bsums[t] = sd[t] - v;         // exclusive block offsets
}

__global__ void k_scan3(int* rowst, int* cursor, const int* bsums, int N, int E) {
  int i = blockIdx.x * 256 + threadIdx.x;
  if (i < N) {
    int v = rowst[i] + bsums[i >> 8];
    rowst[i] = v;
    cursor[i] = v;
  }
  if (i == 0) rowst[N] = E;
}

__global__ void k_place(const int* __restrict__ ei, const int* __restrict__ et,
                        int* cursor, unsigned* packed, int E) {
  int e = blockIdx.x * 256 + threadIdx.x;
  if (e < E) {
    int d = ei[E + e];
    int s = ei[e];
    int r = et[e]; r = r < 0 ? 0 : (r > 1 ? 1 : r);
    int pos = atomicAdd(&cursor[d], 1);
    packed[pos] = (unsigned)s | ((unsigned)r << 30);
  }
}

// e_rel[layer][rel][c] = rel_emb[rel] @ We_layer   (only 2 rel types)
__global__ void k_erel(const float* __restrict__ rel_emb, const float* __restrict__ We1,
                       const float* __restrict__ We2, float* erel) {
  int t = threadIdx.x;  // 512
  int layer = t >> 8, r = (t >> 7) & 1, c = t & 127;
  const float* We = layer ? We2 : We1;
  float s = 0.f;
  for (int i = 0; i < 128; i++) s += rel_emb[r * 128 + i] * We[i * 128 + c];
  erel[t] = s;
}

// =============== stage 1: modality MLPs (desc/tweet) -> m[N,128] cols 0..63 ======
// R2-proven version: 128-thread block, 128-row tile, thread tile 8x4.
// (R3 64-row prefetch variant regressed: WRITE_SIZE 12.5->70MB + 2.4M bank conflicts)
__global__ __launch_bounds__(128) void k_modal(
    const float* __restrict__ desc, const float* __restrict__ tw,
    const float* __restrict__ Wd, const float* __restrict__ bd,
    const float* __restrict__ Wt, const float* __restrict__ bt,
    float* __restrict__ m, int N) {
  __shared__ float As[32][132];   // transposed A chunk: As[k][r]
  __shared__ float Bs[32][33];
  int t = threadIdx.x;
  int phase = blockIdx.y;
  const float* Ag = phase ? tw : desc;
  const float* W  = phase ? Wt : Wd;
  const float* bb = phase ? bt : bd;
  int n0 = blockIdx.x * 128;
  int tx = t & 7, ty = t >> 3;           // cols tx*4.., rows ty*8..
  int tx4 = tx * 4, ty8 = ty * 8;
  float acc[8][4];
#pragma unroll
  for (int i = 0; i < 8; i++)
#pragma unroll
    for (int j = 0; j < 4; j++) acc[i][j] = 0.f;

  for (int kc = 0; kc < 768; kc += 32) {
    __syncthreads();
    {  // stage A transposed: thread t owns row r=t, loads 32 k (8 float4)
      int gr = n0 + t; if (gr > N - 1) gr = N - 1;
      const float4* src = (const float4*)(Ag + (size_t)gr * 768 + kc);
#pragma unroll
      for (int q = 0; q < 8; q++) {
        float4 v = src[q];
        As[q * 4 + 0][t] = v.x; As[q * 4 + 1][t] = v.y;
        As[q * 4 + 2][t] = v.z; As[q * 4 + 3][t] = v.w;
      }
      // stage B: kr = t>>2 (0..31), c8 = (t&3)*8
      int kr = t >> 2, c8 = (t & 3) * 8;
      const float4* ws4 = (const float4*)(W + (size_t)(kc + kr) * 32 + c8);
      *(float4*)&Bs[kr][c8] = ws4[0];
      *(float4*)&Bs[kr][c8 + 4] = ws4[1];
    }
    __syncthreads();
#pragma unroll 4
    for (int k = 0; k < 32; k++) {
      float4 a0 = *(const float4*)&As[k][ty8];
      float4 a1 = *(const float4*)&As[k][ty8 + 4];
      float4 b0 = *(const float4*)&Bs[k][tx4];
      float a[8] = {a0.x, a0.y, a0.z, a0.w, a1.x, a1.y, a1.z, a1.w};
#pragma unroll
      for (int i = 0; i < 8; i++) {
        acc[i][0] += a[i] * b0.x; acc[i][1] += a[i] * b0.y;
        acc[i][2] += a[i] * b0.z; acc[i][3] += a[i] * b0.w;
      }
    }
  }
  float4 bv = *(const float4*)&bb[tx4];
#pragma unroll
  for (int i = 0; i < 8; i++) {
    int gr = n0 + ty8 + i;
    if (gr < N) {
      float4 v;
      v.x = acc[i][0] + bv.x; v.y = acc[i][1] + bv.y;
      v.z = acc[i][2] + bv.z; v.w = acc[i][3] + bv.w;
      v.x = LEAKY(v.x); v.y = LEAKY(v.y); v.z = LEAKY(v.z); v.w = LEAKY(v.w);
      *(float4*)(m + (size_t)gr * 128 + phase * 32 + tx4) = v;
    }
  }
}

// num (Din=5) and cat (Din=3) -> m cols 64..127
__global__ __launch_bounds__(256) void k_numcat(
    const float* __restrict__ nump, const float* __restrict__ catp,
    const float* __restrict__ Wn, const float* __restrict__ bn,
    const float* __restrict__ Wc, const float* __restrict__ bc,
    float* __restrict__ m, int N) {
  int t = threadIdx.x;
  int n0 = blockIdx.x * 64;
  int c = t & 31, ty = t >> 5;
  float bn_ = bn[c], bc_ = bc[c];
#pragma unroll
  for (int j = 0; j < 8; j++) {
    int gr = n0 + ty * 8 + j;
    int gl = gr > N - 1 ? N - 1 : gr;
    float sn = bn_;
#pragma unroll
    for (int i = 0; i < 5; i++) sn += nump[(size_t)gl * 5 + i] * Wn[i * 32 + c];
    float sc = bc_;
#pragma unroll
    for (int i = 0; i < 3; i++) sc += catp[(size_t)gl * 3 + i] * Wc[i * 32 + c];
    if (gr < N) {
      m[(size_t)gr * 128 + 64 + c] = LEAKY(sn);
      m[(size_t)gr * 128 + 96 + c] = LEAKY(sc);
    }
  }
}

// ============ stage 2a: inv/spec projectors -> ch[N,256], aux partials ============
__global__ __launch_bounds__(256) void k_chfuse(
    const float* __restrict__ m, const float* __restrict__ Winv, const float* __restrict__ binv,
    const float* __restrict__ Wspec, const float* __restrict__ bspec,
    float* __restrict__ ch, float* __restrict__ auxp, int N) {
  __shared__ float sm[4][128];
  __shared__ float sch[4][256];
  int t = threadIdx.x;
  int wid = t >> 6, lane = t & 63;
  int n = blockIdx.x * 4 + wid;
  if (n > N - 1) n = N - 1;
  sm[wid][lane] = m[(size_t)n * 128 + lane];
  sm[wid][lane + 64] = m[(size_t)n * 128 + 64 + lane];
  __syncthreads();
#pragma unroll
  for (int p = 0; p < 4; p++) {
    int idx = p * 64 + lane;
    int type = idx >> 7;        // wave-uniform per p
    int k = (idx >> 5) & 3;
    int o = idx & 31;
    const float* W = type ? Wspec : Winv;
    const float* bb = type ? bspec : binv;
    float s = bb[k * 32 + o];
    for (int i = 0; i < 32; i++) s += sm[wid][k * 32 + i] * W[(k * 32 + i) * 32 + o];
    float val = type ? LEAKY(s) : tanhf(s);
    sch[wid][k * 64 + type * 32 + o] = val;  // [tok][inv(32)|spec(32)] = CH layout
  }
  __syncthreads();
  *(float4*)(ch + (size_t)n * 256 + lane * 4) = *(const float4*)&sch[wid][lane * 4];
  // aux partials
  float invp = 0.f;
  float pr[10];
#pragma unroll
  for (int q = 0; q < 10; q++) pr[q] = 0.f;
  if (lane < 32) {
    float i0 = sch[wid][lane],       i1 = sch[wid][64 + lane];
    float i2 = sch[wid][128 + lane], i3 = sch[wid][192 + lane];
    float cm = 0.25f * (i0 + i1 + i2 + i3);
    float d0 = i0 - cm, d1 = i1 - cm, d2 = i2 - cm, d3 = i3 - cm;
    invp = d0 * d0 + d1 * d1 + d2 * d2 + d3 * d3;
    float s0 = sch[wid][32 + lane],  s1 = sch[wid][96 + lane];
    float s2 = sch[wid][160 + lane], s3 = sch[wid][224 + lane];
    pr[0] = s0 * s0; pr[1] = s1 * s1; pr[2] = s2 * s2; pr[3] = s3 * s3;
    pr[4] = s0 * s1; pr[5] = s0 * s2; pr[6] = s0 * s3;
    pr[7] = s1 * s2; pr[8] = s1 * s3; pr[9] = s2 * s3;
  }
#pragma unroll
  for (int off = 1; off < 64; off <<= 1) {
    invp += __shfl_xor(invp, off);
#pragma unroll
    for (int q = 0; q < 10; q++) pr[q] += __shfl_xor(pr[q], off);
  }
  if (lane == 0) {
    float n0_ = sqrtf(pr[0]), n1_ = sqrtf(pr[1]), n2_ = sqrtf(pr[2]), n3_ = sqrtf(pr[3]);
    float ov = fabsf(pr[4] / fmaxf(n0_ * n1_, 1e-8f))
             + fabsf(pr[5] / fmaxf(n0_ * n2_, 1e-8f))
             + fabsf(pr[6] / fmaxf(n0_ * n3_, 1e-8f))
             + fabsf(pr[7] / fmaxf(n1_ * n2_, 1e-8f))
             + fabsf(pr[8] / fmaxf(n1_ * n3_, 1e-8f))
             + fabsf(pr[9] / fmaxf(n2_ * n3_, 1e-8f));
    auxp[n] = invp / 128.f + 0.5f * (ov / 6.f);
  }
}

// ========== stage 2b-1: qkv GEMM (tokens[4N,64] @ Wqkv[64,192]) + channel attn ====
// 128 tokens (32 nodes) per block, 256 threads, 8x12 thread tile. qkv stays in LDS.
__global__ __launch_bounds__(256) void k_qkvattn(
    const float* __restrict__ ch, const float* __restrict__ Wqkv,
    const float* __restrict__ bqkv, float* __restrict__ att, int N4) {
  __shared__ float As[32][132];   // ch chunk, transposed
  __shared__ float Bs[32][200];   // Wqkv chunk
  __shared__ float qb[128][200];  // qkv for 128 tokens (cols: q 0-63, k 64-127, v 128-191)
  int t = threadIdx.x;
  int tok0 = blockIdx.x * 128;
  int tx = t & 15, ty = t >> 4;   // cols tx*12.., rows ty*8..
  float acc[8][12];
#pragma unroll
  for (int i = 0; i < 8; i++)
#pragma unroll
    for (int j = 0; j < 12; j++) acc[i][j] = 0.f;

  for (int kc = 0; kc < 64; kc += 32) {
    __syncthreads();
    {  // stage A transposed: r = t>>1, half = t&1 -> 16 k values
      int r = t >> 1, half = t & 1;
      int gtok = tok0 + r; if (gtok > N4 - 1) gtok = N4 - 1;
      const float4* src = (const float4*)(ch + (size_t)gtok * 64 + kc + half * 16);
      int kb = half * 16;
#pragma unroll
      for (int q = 0; q < 4; q++) {
        float4 v = src[q];
        As[kb + q * 4 + 0][r] = v.x; As[kb + q * 4 + 1][r] = v.y;
        As[kb + q * 4 + 2][r] = v.z; As[kb + q * 4 + 3][r] = v.w;
      }
      // stage B: rows kr, kr+16; cols (t&15)*12
      int kr = t >> 4, cq = (t & 15) * 12;
#pragma unroll
      for (int rr = 0; rr < 2; rr++) {
        int row = kr + rr * 16;
        const float* wsrc = Wqkv + (size_t)(kc + row) * 192 + cq;
        *(float4*)&Bs[row][cq] = *(const float4*)(wsrc);
        *(float4*)&Bs[row][cq + 4] = *(const float4*)(wsrc + 4);
        *(float4*)&Bs[row][cq + 8] = *(const float4*)(wsrc + 8);
      }
    }
    __syncthreads();
#pragma unroll 8
    for (int k = 0; k < 32; k++) {
      float4 a0 = *(const float4*)&As[k][ty * 8];
      float4 a1 = *(const float4*)&As[k][ty * 8 + 4];
      float4 b0 = *(const float4*)&Bs[k][tx * 12];
      float4 b1 = *(const float4*)&Bs[k][tx * 12 + 4];
      float4 b2 = *(const float4*)&Bs[k][tx * 12 + 8];
      float a[8] = {a0.x, a0.y, a0.z, a0.w, a1.x, a1.y, a1.z, a1.w};
      float b[12] = {b0.x, b0.y, b0.z, b0.w, b1.x, b1.y, b1.z, b1.w,
                     b2.x, b2.y, b2.z, b2.w};
#pragma unroll
      for (int i = 0; i < 8; i++)
#pragma unroll
        for (int j = 0; j < 12; j++) acc[i][j] += a[i] * b[j];
    }
  }
  // bias + write qkv to LDS
  float4 bb0 = *(const float4*)&bqkv[tx * 12];
  float4 bb1 = *(const float4*)&bqkv[tx * 12 + 4];
  float4 bb2 = *(const float4*)&bqkv[tx * 12 + 8];
  __syncthreads();
#pragma unroll
  for (int i = 0; i < 8; i++) {
    int row = ty * 8 + i;
    float4 v0, v1, v2;
    v0.x = acc[i][0] + bb0.x; v0.y = acc[i][1] + bb0.y;
    v0.z = acc[i][2] + bb0.z; v0.w = acc[i][3] + bb0.w;
    v1.x = acc[i][4] + bb1.x; v1.y = acc[i][5] + bb1.y;
    v1.z = acc[i][6] + bb1.z; v1.w = acc[i][7] + bb1.w;
    v2.x = acc[i][8] + bb2.x; v2.y = acc[i][9] + bb2.y;
    v2.z = acc[i][10] + bb2.z; v2.w = acc[i][11] + bb2.w;
    *(float4*)&qb[row][tx * 12] = v0;
    *(float4*)&qb[row][tx * 12 + 4] = v1;
    *(float4*)&qb[row][tx * 12 + 8] = v2;
  }
  __syncthreads();
  // channel attention: thread (g,h) handles node g (32/block), head h, all 4 q-tokens
  {
    int g = t >> 3, h = t & 7;
    int rb = g * 4;
    float kk[4][8], vv[4][8];
#pragma unroll
    for (int j = 0; j < 4; j++)
#pragma unroll
      for (int dd = 0; dd < 8; dd++) {
        kk[j][dd] = qb[rb + j][64 + h * 8 + dd];
        vv[j][dd] = qb[rb + j][128 + h * 8 + dd];
      }
#pragma unroll
    for (int qi = 0; qi < 4; qi++) {
      float qv[8];
#pragma unroll
      for (int dd = 0; dd < 8; dd++) qv[dd] = qb[rb + qi][h * 8 + dd];
      float sc[4];
#pragma unroll
      for (int j = 0; j < 4; j++) {
        float s = 0.f;
#pragma unroll
        for (int dd = 0; dd < 8; dd++) s += qv[dd] * kk[j][dd];
        sc[j] = s * 0.35355339059327373f;  // 1/sqrt(8)
      }
      float mx = fmaxf(fmaxf(sc[0], sc[1]), fmaxf(sc[2], sc[3]));
      float e0 = expf(sc[0] - mx), e1 = expf(sc[1] - mx);
      float e2 = expf(sc[2] - mx), e3 = expf(sc[3] - mx);
      float inv = 1.f / (e0 + e1 + e2 + e3);
      int token = tok0 + rb + qi;
      if (token < N4) {
        float o[8];
#pragma unroll
        for (int dd = 0; dd < 8; dd++)
          o[dd] = (e0 * vv[0][dd] + e1 * vv[1][dd] + e2 * vv[2][dd] + e3 * vv[3][dd]) * inv;
        float* dst = att + (size_t)token * 64 + h * 8;
        float4 w0 = {o[0], o[1], o[2], o[3]};
        float4 w1 = {o[4], o[5], o[6], o[7]};
        *(float4*)(dst) = w0;
        *(float4*)(dst + 4) = w1;
      }
    }
  }
}

// ==== stage 2b-2: attn_out GEMM + bias + residual + LN + token-mean + c2h -> x0 ====
// 128 tokens (32 nodes) per block, 256 threads.
__global__ __launch_bounds__(256) void k_attnout(
    const float* __restrict__ att, const float* __restrict__ ch,
    const float* __restrict__ Wao, const float* __restrict__ bao,
    const float* __restrict__ lng, const float* __restrict__ lnb,
    const float* __restrict__ Wc2h, const float* __restrict__ bc2h,
    float* __restrict__ x0, int N, int N4) {
  __shared__ float As[32][132];
  __shared__ float Bs[32][132];
  __shared__ float hmT[64][36];   // transposed node-mean: hmT[k][node]
  int t = threadIdx.x;
  int tok0 = blockIdx.x * 128;
  int tx = t & 15, ty = t >> 4;   // cols tx*4 (of 64), rows ty*8 (of 128)
  float acc[8][4];
#pragma unroll
  for (int i = 0; i < 8; i++)
#pragma unroll
    for (int j = 0; j < 4; j++) acc[i][j] = 0.f;

  for (int kc = 0; kc < 64; kc += 32) {
    __syncthreads();
    {
      int r = t >> 1, half = t & 1;
      int gtok = tok0 + r; if (gtok > N4 - 1) gtok = N4 - 1;
      const float4* src = (const float4*)(att + (size_t)gtok * 64 + kc + half * 16);
      int kb = half * 16;
#pragma unroll
      for (int q = 0; q < 4; q++) {
        float4 v = src[q];
        As[kb + q * 4 + 0][r] = v.x; As[kb + q * 4 + 1][r] = v.y;
        As[kb + q * 4 + 2][r] = v.z; As[kb + q * 4 + 3][r] = v.w;
      }
      int kr = t >> 3, cq = (t & 7) * 8;
      const float4* wsrc = (const float4*)(Wao + (size_t)(kc + kr) * 64 + cq);
      *(float4*)&Bs[kr][cq] = wsrc[0];
      *(float4*)&Bs[kr][cq + 4] = wsrc[1];
    }
    __syncthreads();
#pragma unroll 8
    for (int k = 0; k < 32; k++) {
      float4 a0 = *(const float4*)&As[k][ty * 8];
      float4 a1 = *(const float4*)&As[k][ty * 8 + 4];
      float4 b0 = *(const float4*)&Bs[k][tx * 4];
      float a[8] = {a0.x, a0.y, a0.z, a0.w, a1.x, a1.y, a1.z, a1.w};
#pragma unroll
      for (int i = 0; i < 8; i++) {
        acc[i][0] += a[i] * b0.x; acc[i][1] += a[i] * b0.y;
        acc[i][2] += a[i] * b0.z; acc[i][3] += a[i] * b0.w;
      }
    }
  }
  // bias + residual + LayerNorm
  float4 bv = *(const float4*)&bao[tx * 4];
  float4 g4 = *(const float4*)&lng[tx * 4];
  float4 lb4 = *(const float4*)&lnb[tx * 4];
  float nv[8][4];
#pragma unroll
  for (int i = 0; i < 8; i++) {
    int row = ty * 8 + i;
    int gtok = tok0 + row; if (gtok > N4 - 1) gtok = N4 - 1;
    float4 c4 = *(const float4*)(ch + (size_t)gtok * 64 + tx * 4);
    float y0 = acc[i][0] + bv.x + c4.x;
    float y1 = acc[i][1] + bv.y + c4.y;
    float y2 = acc[i][2] + bv.z + c4.z;
    float y3 = acc[i][3] + bv.w + c4.w;
    float s1 = y0 + y1 + y2 + y3;
    s1 += __shfl_xor(s1, 1); s1 += __shfl_xor(s1, 2);
    s1 += __shfl_xor(s1, 4); s1 += __shfl_xor(s1, 8);
    float mu = s1 * (1.f / 64.f);
    float d0 = y0 - mu, d1 = y1 - mu, d2 = y2 - mu, d3 = y3 - mu;
    float s2 = d0 * d0 + d1 * d1 + d2 * d2 + d3 * d3;
    s2 += __shfl_xor(s2, 1); s2 += __shfl_xor(s2, 2);
    s2 += __shfl_xor(s2, 4); s2 += __shfl_xor(s2, 8);
    float rs = rsqrtf(s2 * (1.f / 64.f) + 1e-5f);
    nv[i][0] = d0 * rs * g4.x + lb4.x;
    nv[i][1] = d1 * rs * g4.y + lb4.y;
    nv[i][2] = d2 * rs * g4.z + lb4.z;
    nv[i][3] = d3 * rs * g4.w + lb4.w;
  }
  // token-mean -> hmT[k][node]  (thread owns 2 nodes x 4 k-cols)
#pragma unroll
  for (int ii = 0; ii < 2; ii++) {
    int node = ty * 2 + ii;
#pragma unroll
    for (int j = 0; j < 4; j++) {
      float mval = 0.25f * (nv[ii * 4 + 0][j] + nv[ii * 4 + 1][j]
                          + nv[ii * 4 + 2][j] + nv[ii * 4 + 3][j]);
      hmT[tx * 4 + j][node] = mval;
    }
  }
  // c2h GEMM: hm[32,64] @ Wc2h[64,128] -> leaky -> x0
  int tx2 = t & 31, ty2 = t >> 5;   // cols tx2*4 (of 128), nodes ty2*4 (of 32)
  float acc2[4][4];
#pragma unroll
  for (int i = 0; i < 4; i++)
#pragma unroll
    for (int j = 0; j < 4; j++) acc2[i][j] = 0.f;
  for (int kc = 0; kc < 64; kc += 32) {
    __syncthreads();
    {
      int kr = t >> 3, cq = (t & 7) * 16;
      const float4* wsrc = (const float4*)(Wc2h + (size_t)(kc + kr) * 128 + cq);
      *(float4*)&Bs[kr][cq] = wsrc[0];
      *(float4*)&Bs[kr][cq + 4] = wsrc[1];
      *(float4*)&Bs[kr][cq + 8] = wsrc[2];
      *(float4*)&Bs[kr][cq + 12] = wsrc[3];
    }
    __syncthreads();
#pragma unroll 8
    for (int kk = 0; kk < 32; kk++) {
      float4 a = *(const float4*)&hmT[kc + kk][ty2 * 4];
      float4 b = *(const float4*)&Bs[kk][tx2 * 4];
      float av[4] = {a.x, a.y, a.z, a.w};
#pragma unroll
      for (int i = 0; i < 4; i++) {
        acc2[i][0] += av[i] * b.x; acc2[i][1] += av[i] * b.y;
        acc2[i][2] += av[i] * b.z; acc2[i][3] += av[i] * b.w;
      }
    }
  }
  float4 bc4 = *(const float4*)&bc2h[tx2 * 4];
  int nb0 = blockIdx.x * 32;
#pragma unroll
  for (int i = 0; i < 4; i++) {
    int gn = nb0 + ty2 * 4 + i;
    if (gn < N) {
      float4 v;
      v.x = acc2[i][0] + bc4.x; v.y = acc2[i][1] + bc4.y;
      v.z = acc2[i][2] + bc4.z; v.w = acc2[i][3] + bc4.w;
      v.x = LEAKY(v.x); v.y = LEAKY(v.y); v.z = LEAKY(v.z); v.w = LEAKY(v.w);
      *(float4*)(x0 + (size_t)gn * 128 + tx2 * 4) = v;
    }
  }
}

// ====== register-tiled GEMM: out[:, cb*128..] = x[N,128] @ W_cb + b_cb =========
__global__ __launch_bounds__(256) void k_gemm(
    const float* __restrict__ x,
    const float* __restrict__ W0, const float* __restrict__ B0,
    const float* __restrict__ W1, const float* __restrict__ B1,
    const float* __restrict__ W2, const float* __restrict__ B2,
    const float* __restrict__ W3, const float* __restrict__ B3,
    float* __restrict__ out, int N, int ostride, int do_leaky) {
  __shared__ float As[32][132];   // As[k][r] transposed
  __shared__ float Bs[32][132];   // Bs[k][c]
  int t = threadIdx.x;
  int cb = blockIdx.y;
  const float* W = (cb == 0) ? W0 : (cb == 1) ? W1 : (cb == 2) ? W2 : W3;
  const float* bias = (cb == 0) ? B0 : (cb == 1) ? B1 : (cb == 2) ? B2 : B3;
  int n0 = blockIdx.x * 128;
  int tx = t & 15, ty = t >> 4;
  int tx4 = tx * 4, ty4 = (ty & 15) * 4;
  float acc[8][8];
#pragma unroll
  for (int i = 0; i < 8; i++)
#pragma unroll
    for (int j = 0; j < 8; j++) acc[i][j] = 0.f;

  for (int kc = 0; kc < 128; kc += 32) {
    __syncthreads();
    {
      int r = t >> 1, half = t & 1;
      int gr = n0 + r; if (gr > N - 1) gr = N - 1;
      const float4* src = (const float4*)(x + (size_t)gr * 128 + kc + half * 16);
      int kb = half * 16;
#pragma unroll
      for (int q = 0; q < 4; q++) {
        float4 v = src[q];
        As[kb + q * 4 + 0][r] = v.x; As[kb + q * 4 + 1][r] = v.y;
        As[kb + q * 4 + 2][r] = v.z; As[kb + q * 4 + 3][r] = v.w;
      }
      int kr = t >> 3, cq = (t & 7) * 16;
      const float4* ws4 = (const float4*)(W + (size_t)(kc + kr) * 128 + cq);
      *(float4*)&Bs[kr][cq] = ws4[0];
      *(float4*)&Bs[kr][cq + 4] = ws4[1];
      *(float4*)&Bs[kr][cq + 8] = ws4[2];
      *(float4*)&Bs[kr][cq + 12] = ws4[3];
    }
    __syncthreads();
#pragma unroll 4
    for (int k = 0; k < 32; k++) {
      float4 a0 = *(const float4*)&As[k][ty4];
      float4 a1 = *(const float4*)&As[k][64 + ty4];
      float4 b0 = *(const float4*)&Bs[k][tx4];
      float4 b1 = *(const float4*)&Bs[k][64 + tx4];
      float a[8] = {a0.x, a0.y, a0.z, a0.w, a1.x, a1.y, a1.z, a1.w};
      float b[8] = {b0.x, b0.y, b0.z, b0.w, b1.x, b1.y, b1.z, b1.w};
#pragma unroll
      for (int i = 0; i < 8; i++)
#pragma unroll
        for (int j = 0; j < 8; j++) acc[i][j] += a[i] * b[j];
    }
  }
  float4 bv0 = *(const float4*)&bias[tx4];
  float4 bv1 = *(const float4*)&bias[64 + tx4];
#pragma unroll
  for (int i = 0; i < 8; i++) {
    int r = (i < 4) ? (ty4 + i) : (60 + ty4 + i);
    int gr = n0 + r;
    if (gr < N) {
      float4 v0, v1;
      v0.x = acc[i][0] + bv0.x; v0.y = acc[i][1] + bv0.y;
      v0.z = acc[i][2] + bv0.z; v0.w = acc[i][3] + bv0.w;
      v1.x = acc[i][4] + bv1.x; v1.y = acc[i][5] + bv1.y;
      v1.z = acc[i][6] + bv1.z; v1.w = acc[i][7] + bv1.w;
      if (do_leaky) {
        v0.x = LEAKY(v0.x); v0.y = LEAKY(v0.y); v0.z = LEAKY(v0.z); v0.w = LEAKY(v0.w);
        v1.x = LEAKY(v1.x); v1.y = LEAKY(v1.y); v1.z = LEAKY(v1.z); v1.w = LEAKY(v1.w);
      }
      float* o = out + (size_t)gr * ostride + (size_t)cb * 128;
      *(float4*)(o + tx4) = v0;
      *(float4*)(o + 64 + tx4) = v1;
    }
  }
}

// ====== TransformerConv aggregation: one wave per dst node (CSR, no atomics) ======
// Software-pipelined: edge e+1's gathers issue before edge e's reduce chain.
__global__ __launch_bounds__(256) void k_conv(
    const float* __restrict__ qkvs, const int* __restrict__ rowst,
    const unsigned* __restrict__ packed, const float* __restrict__ erelL,
    float* __restrict__ xout, int N, int do_leaky) {
  __shared__ float se[2][128];
  int t = threadIdx.x;
  se[t >> 7][t & 127] = erelL[t];
  __syncthreads();
  int wid = t >> 6, lane = t & 63;
  int d = blockIdx.x * 4 + wid;
  if (d >= N) return;
  const float* qb = qkvs + (size_t)d * 512;
  float q0 = qb[lane], q1 = qb[64 + lane];
  int e0 = rowst[d], e1 = rowst[d + 1];
  float acc0 = 0.f, acc1 = 0.f, den0 = 0.f, den1 = 0.f;
  if (e0 < e1) {
    // prologue: load edge e0
    unsigned pk = packed[e0];
    const float* sb = qkvs + (size_t)(pk & 0x0FFFFFFFu) * 512;
    int rel = (int)(pk >> 30);
    float k0 = sb[128 + lane], k1 = sb[192 + lane];
    float v0 = sb[256 + lane], v1 = sb[320 + lane];
    for (int e = e0; e < e1; e++) {
      float ck0 = k0, ck1 = k1, cv0 = v0, cv1 = v1;
      int crel = rel;
      if (e + 1 < e1) {  // issue next edge's gathers now (overlap with reduce below)
        unsigned pk2 = packed[e + 1];
        const float* sb2 = qkvs + (size_t)(pk2 & 0x0FFFFFFFu) * 512;
        rel = (int)(pk2 >> 30);
        k0 = sb2[128 + lane]; k1 = sb2[192 + lane];
        v0 = sb2[256 + lane]; v1 = sb2[320 + lane];
      }
      float ek0 = se[crel][lane], ek1 = se[crel][64 + lane];
      float kk0 = ck0 + ek0, kk1 = ck1 + ek1;
      float vv0 = cv0 + ek0, vv1 = cv1 + ek1;
      float p0 = q0 * kk0, p1 = q1 * kk1;
#pragma unroll
      for (int off = 1; off < 16; off <<= 1) {  // per-head (16-ch) reduce
        p0 += __shfl_xor(p0, off);
        p1 += __shfl_xor(p1, off);
      }
      float ex0 = expf(p0 * 0.25f);  // 1/sqrt(16); no max-sub needed (|alpha| small)
      float ex1 = expf(p1 * 0.25f);
      acc0 += ex0 * vv0; den0 += ex0;
      acc1 += ex1 * vv1; den1 += ex1;
    }
  }
  float o0 = acc0 / (den0 + 1e-16f) + qb[384 + lane];
  float o1 = acc1 / (den1 + 1e-16f) + qb[448 + lane];
  if (do_leaky) { o0 = LEAKY(o0); o1 = LEAKY(o1); }
  xout[(size_t)d * 128 + lane] = o0;
  xout[(size_t)d * 128 + 64 + lane] = o1;
}

// ============== head: logits = x3 @ Whead + bhead  (32 nodes/block) ==============
__global__ __launch_bounds__(256) void k_head(
    const float* __restrict__ x3, const float* __restrict__ Wh,
    const float* __restrict__ bh, float* __restrict__ out, int N) {
  int t = threadIdx.x;
  int node = blockIdx.x * 32 + (t >> 3);
  int l8 = t & 7;
  int gl = node < N ? node : N - 1;
  const float4* xr = (const float4*)(x3 + (size_t)gl * 128 + l8 * 16);
  float h0 = 0.f, h1 = 0.f;
#pragma unroll
  for (int q = 0; q < 4; q++) {
    float4 v = xr[q];
    int kb = (l8 * 16 + q * 4) * 2;
    h0 += v.x * Wh[kb] + v.y * Wh[kb + 2] + v.z * Wh[kb + 4] + v.w * Wh[kb + 6];
    h1 += v.x * Wh[kb + 1] + v.y * Wh[kb + 3] + v.z * Wh[kb + 5] + v.w * Wh[kb + 7];
  }
#pragma unroll
  for (int off = 1; off < 8; off <<= 1) {
    h0 += __shfl_xor(h0, off);
    h1 += __shfl_xor(h1, off);
  }
  if (l8 == 0 && node < N) {
    float2 r; r.x = h0 + bh[0]; r.y = h1 + bh[1];
    *(float2*)(out + (size_t)node * 2) = r;
  }
}

__global__ void k_aux(const float* __restrict__ auxp, float* __restrict__ out, int N) {
  __shared__ float sd[256];
  int t = threadIdx.x;
  float s = 0.f;
  for (int i = t; i < N; i += 256) s += auxp[i];
  sd[t] = s;
  __syncthreads();
  for (int off = 128; off > 0; off >>= 1) {
    if (t < off) sd[t] += sd[t + off];
    __syncthreads();
  }
  if (t == 0) out[0] = 0.1f * sd[0] / (float)N;
}

extern "C" void kernel_launch(void* const* d_in, const int* in_sizes, int n_in,
                              void* d_out, int out_size, void* d_ws, size_t ws_size,
                              hipStream_t stream) {
  (void)n_in; (void)out_size; (void)ws_size;
  const float* desc = (const float*)d_in[0];
  const float* tw   = (const float*)d_in[1];
  const float* nump = (const float*)d_in[2];
  const float* catp = (const float*)d_in[3];
  const int* ei = (const int*)d_in[4];
  const int* et = (const int*)d_in[5];
  const float* Wd = (const float*)d_in[6];  const float* bd = (const float*)d_in[7];
  const float* Wt = (const float*)d_in[8];  const float* bt = (const float*)d_in[9];
  const float* Wn = (const float*)d_in[10]; const float* bn = (const float*)d_in[11];
  const float* Wc = (const float*)d_in[12]; const float* bc = (const float*)d_in[13];
  const float* Winv = (const float*)d_in[14]; const float* binv = (const float*)d_in[15];
  const float* Wspec = (const float*)d_in[16]; const float* bspec = (const float*)d_in[17];
  const float* Wqkv = (const float*)d_in[18]; const float* bqkv = (const float*)d_in[19];
  const float* Wao = (const float*)d_in[20]; const float* bao = (const float*)d_in[21];
  const float* lng = (const float*)d_in[22]; const float* lnb = (const float*)d_in[23];
  const float* Wc2h = (const float*)d_in[24]; const float* bc2h = (const float*)d_in[25];
  const float* rel_emb = (const float*)d_in[26];
  const float* Wq1 = (const float*)d_in[27]; const float* bq1 = (const float*)d_in[28];
  const float* Wk1 = (const float*)d_in[29]; const float* bk1 = (const float*)d_in[30];
  const float* Wv1 = (const float*)d_in[31]; const float* bv1 = (const float*)d_in[32];
  const float* We1 = (const float*)d_in[33];
  const float* Ws1 = (const float*)d_in[34]; const float* bs1 = (const float*)d_in[35];
  const float* Wq2 = (const float*)d_in[36]; const float* bq2 = (const float*)d_in[37];
  const float* Wk2 = (const float*)d_in[38]; const float* bk2 = (const float*)d_in[39];
  const float* Wv2 = (const float*)d_in[40]; const float* bv2 = (const float*)d_in[41];
  const float* We2 = (const float*)d_in[42];
  const float* Ws2 = (const float*)d_in[43]; const float* bs2 = (const float*)d_in[44];
  const float* Wout = (const float*)d_in[45]; const float* bout = (const float*)d_in[46];
  const float* Whead = (const float*)d_in[47]; const float* bhead = (const float*)d_in[48];

  int N = in_sizes[0] / 768;
  int E = in_sizes[5];
  int N4 = N * 4;
  float* out = (float*)d_out;

  // workspace layout (fp32): ~208 MB total
  float* ws = (float*)d_ws;
  size_t Ns = (size_t)N;
  float* m_buf    = ws;                    // N*128
  float* ch_buf   = m_buf + Ns * 128;      // N*256
  float* x0_buf   = ch_buf + Ns * 256;     // N*128
  float* qkvs_buf = x0_buf + Ns * 128;     // N*512
  float* auxp     = qkvs_buf + Ns * 512;   // N
  float* erel     = auxp + Ns;             // 512
  int* counts = (int*)(erel + 512);        // N
  int* rowst  = counts + N;                // N+1
  int* cursor = rowst + N + 1;             // N
  unsigned* packed = (unsigned*)(cursor + N);  // E
  int* bsums  = (int*)(packed + E);        // NB
  float* x1_buf = m_buf;                   // reuse (m dead after k_chfuse)
  float* x2_buf = ch_buf;                  // reuse (ch dead after k_attnout)
  float* x3_buf = x0_buf;                  // reuse (x0 dead after first k_gemm)
  float* att_buf = qkvs_buf;               // reuse (qkvs dead during stage2b)

  int NB = (N + 255) / 256;
  int EB = (E + 255) / 256;
  int GT = (N + 127) / 128;                // 128-row GEMM tiles
  int TT = (N4 + 127) / 128;               // 128-token tiles

  k_zero<<<NB, 256, 0, stream>>>(counts, N);
  k_count<<<EB, 256, 0, stream>>>(ei, counts, E);
  k_scan1<<<NB, 256, 0, stream>>>(counts, rowst, bsums, N);
  k_scan2<<<1, 256, 0, stream>>>(bsums, NB);
  k_scan3<<<NB, 256, 0, stream>>>(rowst, cursor, bsums, N, E);
  k_place<<<EB, 256, 0, stream>>>(ei, et, cursor, packed, E);
  k_erel<<<1, 512, 0, stream>>>(rel_emb, We1, We2, erel);

  k_modal<<<dim3(GT, 2), 128, 0, stream>>>(desc, tw, Wd, bd, Wt, bt, m_buf, N);
  k_numcat<<<(N + 63) / 64, 256, 0, stream>>>(nump, catp, Wn, bn, Wc, bc, m_buf, N);
  k_chfuse<<<(N + 3) / 4, 256, 0, stream>>>(m_buf, Winv, binv, Wspec, bspec,
      ch_buf, auxp, N);
  k_qkvattn<<<TT, 256, 0, stream>>>(ch_buf, Wqkv, bqkv, att_buf, N4);
  k_attnout<<<TT, 256, 0, stream>>>(att_buf, ch_buf, Wao, bao, lng, lnb,
      Wc2h, bc2h, x0_buf, N, N4);

  k_gemm<<<dim3(GT, 4), 256, 0, stream>>>(x0_buf, Wq1, bq1, Wk1, bk1,
      Wv1, bv1, Ws1, bs1, qkvs_buf, N, 512, 0);
  k_conv<<<(N + 3) / 4, 256, 0, stream>>>(qkvs_buf, rowst, packed, erel, x1_buf, N, 1);
  k_gemm<<<dim3(GT, 4), 256, 0, stream>>>(x1_buf, Wq2, bq2, Wk2, bk2,
      Wv2, bv2, Ws2, bs2, qkvs_buf, N, 512, 0);
  k_conv<<<(N + 3) / 4, 256, 0, stream>>>(qkvs_buf, rowst, packed, erel + 256, x2_buf, N, 0);

  k_gemm<<<dim3(GT, 1), 256, 0, stream>>>(x2_buf, Wout, bout, Wout, bout,
      Wout, bout, Wout, bout, x3_buf, N, 128, 1);
  k_head<<<(N + 31) / 32, 256, 0, stream>>>(x3_buf, Whead, bhead, out, N);
  k_aux<<<1, 256, 0, stream>>>(auxp, out + (size_t)2 * N, N);
}